// Round 7
// baseline (2418.829 us; speedup 1.0000x reference)
//
#include <hip/hip_runtime.h>

typedef unsigned short u16;
typedef unsigned int   u32;
typedef unsigned long long u64;
typedef short s16x8 __attribute__((ext_vector_type(8)));
typedef float f32x4 __attribute__((ext_vector_type(4)));

#define S_LEN 2048
#define BATCH 64
#define H_DIM 300
#define HP    304   // padded N (output) dim
#define KP    320   // padded K (contraction) dim for xp_gemm

// ws layout (bytes)
#define OFF_WPAD 0u         // 304*320*2 = 194,560
#define OFF_BIAS 196608u    // 304*4
#define OFF_FLAG 198656u    // 4
#define OFF_H    200704u    // 64*304*4 = 77,824
#define OFF_POOL 278528u    // 2048*304*4 = 2,490,368
#define OFF_WHH  2768896u   // 320*304*4 = 389,120
#define OFF_XP   3158016u   // CH*64*304*4 (f32)

__device__ __forceinline__ float bf2f(u16 u){
  union { u32 i; float f; } v; v.i = ((u32)u) << 16; return v.f;
}
__device__ __forceinline__ u16 f2bf(float f){
  u32 i = __float_as_uint(f);
  u32 r = (i + 0x7fffu + ((i >> 16) & 1u)) >> 16;
  return (u16)r;
}
__device__ __forceinline__ f32x4 fma4(f32x4 a, f32x4 b, f32x4 c){
#if __has_builtin(__builtin_elementwise_fma)
  return __builtin_elementwise_fma(a, b, c);
#else
  f32x4 r; r.x=fmaf(a.x,b.x,c.x); r.y=fmaf(a.y,b.y,c.y);
  r.z=fmaf(a.z,b.z,c.z); r.w=fmaf(a.w,b.w,c.w); return r;
#endif
}

// ---------------------------------------------------------------------------
// detect: f32 vs bf16 input storage (bf16 emb exponents < 135 always).
// ---------------------------------------------------------------------------
__global__ __launch_bounds__(256) void detect(const u16* __restrict__ emb_raw,
                                              int* __restrict__ flag){
  __shared__ int big;
  if (threadIdx.x == 0) big = 0;
  __syncthreads();
  int loc = 0;
  for (int i = threadIdx.x; i < 1024; i += 256){
    const u32 e = ((u32)emb_raw[i] >> 7) & 0xFFu;
    if (e >= 135u) loc = 1;
  }
  if (loc) atomicOr(&big, 1);
  __syncthreads();
  if (threadIdx.x == 0) *flag = big;   // 1 = f32 inputs, 0 = bf16 inputs
}

// ---------------------------------------------------------------------------
// prep: zero pooled/hstate; padded bf16 W_ih [304][320]; fused fp32 bias;
// zero-padded f32 W_hh [320 rows][304 cols].
// ---------------------------------------------------------------------------
__global__ __launch_bounds__(256) void prep(
    const void* __restrict__ Wih_raw, const void* __restrict__ Whh_raw,
    const void* __restrict__ bih_raw, const void* __restrict__ bhh_raw,
    const int* __restrict__ flag,
    u16* __restrict__ Wpad, float* __restrict__ Whh32,
    float* __restrict__ biasp, float* __restrict__ pooled,
    float* __restrict__ hstate)
{
  const bool isf32 = (*flag != 0);
  const int idx = blockIdx.x * 256 + threadIdx.x;
  if (idx < S_LEN * HP) pooled[idx] = 0.f;
  if (idx < BATCH * HP) hstate[idx] = 0.f;
  if (idx < 320 * 304){
    const int r = idx / 304, k = idx % 304;
    float wv = 0.f;
    if (r < H_DIM && k < H_DIM){
      wv = isf32 ? ((const float*)Whh_raw)[r * H_DIM + k]
                 : bf2f(((const u16*)Whh_raw)[r * H_DIM + k]);
    }
    Whh32[idx] = wv;
  }
  if (idx < HP * KP){
    const int n = idx / KP, k = idx % KP;
    u16 v = 0;
    if (n < H_DIM && k < H_DIM){
      v = isf32 ? f2bf(((const float*)Wih_raw)[n * H_DIM + k])
                : ((const u16*)Wih_raw)[n * H_DIM + k];
    }
    Wpad[idx] = v;
  }
  if (idx < HP){
    float bv = 0.f;
    if (idx < H_DIM){
      bv = isf32 ? (((const float*)bih_raw)[idx] + ((const float*)bhh_raw)[idx])
                 : (bf2f(((const u16*)bih_raw)[idx]) + bf2f(((const u16*)bhh_raw)[idx]));
    }
    biasp[idx] = bv;
  }
}

// ---------------------------------------------------------------------------
// xp_gemm: xp[mrel][n] = emb[x[s0*64+mrel]] . W_ih[n,:] + b_ih[n] + b_hh[n]
// One block = 64 m-rows, 4 waves, MFMA 16x16x32 bf16. xp stored f32.
// ---------------------------------------------------------------------------
__global__ __launch_bounds__(256) void xp_gemm(
    const int* __restrict__ x, const void* __restrict__ emb_raw,
    const int* __restrict__ flag,
    const u16* __restrict__ Wpad, const float* __restrict__ biasp,
    float* __restrict__ xp, int s0)
{
  __shared__ u16 A[64 * KP];                 // 40 KB
  const bool isf32 = (*flag != 0);
  const int tid = threadIdx.x;
  const int m0g = s0 * BATCH + blockIdx.x * 64;   // global m of row 0
  const int m0r = blockIdx.x * 64;                // chunk-relative

  for (int t = tid; t < 640; t += 256){
    const int row = t / 10, wd = t % 10;
    *(u32*)&A[row * KP + H_DIM + wd * 2] = 0u;
  }
  for (int t = tid; t < 64 * 75; t += 256){
    const int row = t / 75, off = t % 75;
    const int tok = x[m0g + row];
    u64 pk;
    if (isf32){
      const float4 v = *(const float4*)((const float*)emb_raw + (size_t)tok * H_DIM + off * 4);
      pk = (u64)f2bf(v.x) | ((u64)f2bf(v.y) << 16)
         | ((u64)f2bf(v.z) << 32) | ((u64)f2bf(v.w) << 48);
    } else {
      pk = *(const u64*)((const u16*)emb_raw + (size_t)tok * H_DIM + off * 4);
    }
    *(u64*)&A[row * KP + off * 4] = pk;
  }
  __syncthreads();

  const int wave = tid >> 6, lane = tid & 63;
  const int lm = lane & 15, lq = lane >> 4;

  f32x4 acc[19];
#pragma unroll
  for (int nt = 0; nt < 19; ++nt) acc[nt] = (f32x4){0.f, 0.f, 0.f, 0.f};

#pragma unroll
  for (int ks = 0; ks < 10; ++ks){
    const int k = ks * 32 + lq * 8;
    const s16x8 af = *(const s16x8*)&A[(wave * 16 + lm) * KP + k];
#pragma unroll
    for (int nt = 0; nt < 19; ++nt){
      const s16x8 bf = *(const s16x8*)&Wpad[(nt * 16 + lm) * KP + k];
      acc[nt] = __builtin_amdgcn_mfma_f32_16x16x32_bf16(af, bf, acc[nt], 0, 0, 0);
    }
  }
#pragma unroll
  for (int nt = 0; nt < 19; ++nt){
    const int n = nt * 16 + lm;
    const float bv = biasp[n];
#pragma unroll
    for (int rr = 0; rr < 4; ++rr){
      const int m = m0r + wave * 16 + lq * 4 + rr;
      xp[(size_t)m * HP + n] = acc[nt][rr] + bv;
    }
  }
}

// ---------------------------------------------------------------------------
// recur: one block per batch b. 768 threads = 12 waves. Wave c owns k-chunk
// [25c, 25c+25); lane l owns rows {4l..4l+3, 256+l}. 125 weights/thread in
// VGPRs. amdgpu_waves_per_eu(3,3) pins the occupancy target (VGPR budget
// 168) — the plain launch_bounds min-waves form let the backend target 6-8
// waves/EU and remat the weight loads into the loop (R5/R6: L2-BW bound).
// asm "+v" pins make the loads non-rematerializable. h broadcast via
// readlane->SGPR; FMAs are f32x4 (v_pk_fma_f32).
// ---------------------------------------------------------------------------
#define RL(J) __uint_as_float(__builtin_amdgcn_readlane(hu, (J)))
#define PIN(x) asm("" : "+v"(x))

__global__ __attribute__((amdgpu_flat_work_group_size(768, 768),
                          amdgpu_waves_per_eu(3, 3)))
void recur(
    const float* __restrict__ xp, const float* __restrict__ Whh32,
    float* __restrict__ hstate, float* __restrict__ pooled,
    float* __restrict__ dout, int s0, int len)
{
  const int b   = blockIdx.x;
  const int tid = threadIdx.x;
  const int c   = tid >> 6;        // k-chunk 0..11
  const int l   = tid & 63;
  const int k0  = c * 25;
  const int r0  = l * 4;           // rows r0..r0+3
  const int r4  = 256 + l;         // 5th row (300..319 are zero pad rows)

  __shared__ float hf[320];
  __shared__ float part[12 * 320];

  f32x4 w00,w01,w02,w03,w04,w05;
  f32x4 w10,w11,w12,w13,w14,w15;
  f32x4 w20,w21,w22,w23,w24,w25;
  f32x4 w30,w31,w32,w33,w34,w35;
  f32x4 w40,w41,w42,w43,w44,w45;
  float e0,e1,e2,e3,e4;

#define LOADW(R, ROW) { const float* wp = Whh32 + (size_t)(ROW) * 304 + k0;   \
  w##R##0 = *(const f32x4*)(wp + 0);                                          \
  w##R##1 = *(const f32x4*)(wp + 4);                                          \
  w##R##2 = *(const f32x4*)(wp + 8);                                          \
  w##R##3 = *(const f32x4*)(wp + 12);                                         \
  w##R##4 = *(const f32x4*)(wp + 16);                                         \
  w##R##5 = *(const f32x4*)(wp + 20);                                         \
  e##R = wp[24]; }
  LOADW(0, r0)
  LOADW(1, r0 + 1)
  LOADW(2, r0 + 2)
  LOADW(3, r0 + 3)
  LOADW(4, r4)
#undef LOADW
  PIN(w00); PIN(w01); PIN(w02); PIN(w03); PIN(w04); PIN(w05);
  PIN(w10); PIN(w11); PIN(w12); PIN(w13); PIN(w14); PIN(w15);
  PIN(w20); PIN(w21); PIN(w22); PIN(w23); PIN(w24); PIN(w25);
  PIN(w30); PIN(w31); PIN(w32); PIN(w33); PIN(w34); PIN(w35);
  PIN(w40); PIN(w41); PIN(w42); PIN(w43); PIN(w44); PIN(w45);
  PIN(e0); PIN(e1); PIN(e2); PIN(e3); PIN(e4);

  const float* xpb = xp + (size_t)b * HP;        // chunk row t -> t*64+b
  f32x4 xv = (f32x4){0.f,0.f,0.f,0.f};
  if (tid < 76){
    *(f32x4*)&hf[4 * tid] = *(const f32x4*)&hstate[b * HP + 4 * tid];
    xv = *(const f32x4*)&xpb[4 * tid];
  }
  __syncthreads();

  for (int t = 0; t < len; ++t){
    f32x4 xnext = (f32x4){0.f,0.f,0.f,0.f};
    if (tid < 76){
      const int tn = (t + 1 < len) ? (t + 1) : t;
      xnext = *(const f32x4*)&xpb[(size_t)tn * (BATCH * HP) + 4 * tid];
    }

    const float hl = hf[k0 + (l < 25 ? l : 0)];
    const u32 hu = __float_as_uint(hl);

    f32x4 a0 = (f32x4){0.f,0.f,0.f,0.f};
    f32x4 a1 = a0, a2 = a0, a3 = a0, a4 = a0;
#define DOTP(P) { const f32x4 hv = (f32x4){RL(4*(P)), RL(4*(P)+1), RL(4*(P)+2), RL(4*(P)+3)}; \
    a0 = fma4(w0##P, hv, a0); a1 = fma4(w1##P, hv, a1); a2 = fma4(w2##P, hv, a2);             \
    a3 = fma4(w3##P, hv, a3); a4 = fma4(w4##P, hv, a4); }
    DOTP(0) DOTP(1) DOTP(2) DOTP(3) DOTP(4) DOTP(5)
#undef DOTP
    const float h24 = RL(24);
    const f32x4 sv = (f32x4){
      fmaf(e0, h24, (a0.x + a0.y) + (a0.z + a0.w)),
      fmaf(e1, h24, (a1.x + a1.y) + (a1.z + a1.w)),
      fmaf(e2, h24, (a2.x + a2.y) + (a2.z + a2.w)),
      fmaf(e3, h24, (a3.x + a3.y) + (a3.z + a3.w))};
    const float s4 = fmaf(e4, h24, (a4.x + a4.y) + (a4.z + a4.w));

    *(f32x4*)&part[c * 320 + r0] = sv;
    part[c * 320 + r4] = s4;
    __syncthreads();

    if (tid < 76){
      f32x4 acc = xv;
#pragma unroll
      for (int cc = 0; cc < 12; ++cc) acc += *(const f32x4*)&part[cc * 320 + 4 * tid];
      acc.x = fmaxf(acc.x, 0.f); acc.y = fmaxf(acc.y, 0.f);
      acc.z = fmaxf(acc.z, 0.f); acc.w = fmaxf(acc.w, 0.f);
      const int s = s0 + t;
      if (tid < 75){
        u32* pb = (u32*)(pooled + (size_t)s * HP + 4 * tid);
        atomicMax(pb + 0, __float_as_uint(acc.x));
        atomicMax(pb + 1, __float_as_uint(acc.y));
        atomicMax(pb + 2, __float_as_uint(acc.z));
        atomicMax(pb + 3, __float_as_uint(acc.w));
        if (s == S_LEN - 1)
          *(f32x4*)&dout[S_LEN * 2 + b * H_DIM + 4 * tid] = acc;
      }
      *(f32x4*)&hf[4 * tid] = acc;
      xv = xnext;
    }
    __syncthreads();
  }
  if (tid < 76) *(f32x4*)&hstate[b * HP + 4 * tid] = *(const f32x4*)&hf[4 * tid];
}

// ---------------------------------------------------------------------------
// outproj: out[s][c] = sum_i pooled[s][i] * W_out[c][i] + b_out[c]  (f32 out)
// ---------------------------------------------------------------------------
__global__ __launch_bounds__(128) void outproj(
    const float* __restrict__ pooled, const void* __restrict__ Wout_raw,
    const void* __restrict__ bout_raw, const int* __restrict__ flag,
    float* __restrict__ dout)
{
  const bool isf32 = (*flag != 0);
  const int s = blockIdx.x * 128 + threadIdx.x;   // 0..2047
  float a0, a1;
  if (isf32){ a0 = ((const float*)bout_raw)[0]; a1 = ((const float*)bout_raw)[1]; }
  else      { a0 = bf2f(((const u16*)bout_raw)[0]); a1 = bf2f(((const u16*)bout_raw)[1]); }
  for (int i = 0; i < H_DIM; ++i){
    const float p = pooled[(size_t)s * HP + i];
    float w0, w1;
    if (isf32){ w0 = ((const float*)Wout_raw)[i]; w1 = ((const float*)Wout_raw)[H_DIM + i]; }
    else      { w0 = bf2f(((const u16*)Wout_raw)[i]); w1 = bf2f(((const u16*)Wout_raw)[H_DIM + i]); }
    a0 = fmaf(p, w0, a0);
    a1 = fmaf(p, w1, a1);
  }
  dout[s * 2 + 0] = a0;
  dout[s * 2 + 1] = a1;
}

// ---------------------------------------------------------------------------
extern "C" void kernel_launch(void* const* d_in, const int* in_sizes, int n_in,
                              void* d_out, int out_size, void* d_ws, size_t ws_size,
                              hipStream_t stream)
{
  const int* x  = (const int*)d_in[0];
  const void* emb  = d_in[1];
  const void* Wih  = d_in[2];
  const void* Whh  = d_in[3];
  const void* bih  = d_in[4];
  const void* bhh  = d_in[5];
  const void* Wout = d_in[6];
  const void* bout = d_in[7];
  float* out = (float*)d_out;

  char* ws = (char*)d_ws;
  u16*   Wpad   = (u16*)(ws + OFF_WPAD);
  float* biasp  = (float*)(ws + OFF_BIAS);
  int*   flag   = (int*)(ws + OFF_FLAG);
  float* hstate = (float*)(ws + OFF_H);
  float* pooled = (float*)(ws + OFF_POOL);
  float* Whh32  = (float*)(ws + OFF_WHH);
  float* xp     = (float*)(ws + OFF_XP);

  // choose chunk size (steps) so OFF_XP + CH*64*304*4 fits in ws_size
  const size_t per_step = (size_t)BATCH * HP * 4;   // 77,824 B
  int CH = 16;
  const int cands[8] = {2048, 1024, 512, 256, 128, 64, 32, 16};
  for (int i = 0; i < 8; ++i){
    if ((size_t)OFF_XP + (size_t)cands[i] * per_step <= ws_size){ CH = cands[i]; break; }
  }
  const int nchunks = S_LEN / CH;

  detect<<<1, 256, 0, stream>>>((const u16*)emb, flag);
  prep<<<2432, 256, 0, stream>>>(Wih, Whh, bih, bhh, flag, Wpad, Whh32,
                                 biasp, pooled, hstate);
  for (int k = 0; k < nchunks; ++k){
    const int s0 = k * CH;
    xp_gemm<<<CH, 256, 0, stream>>>(x, emb, flag, Wpad, biasp, xp, s0);
    recur<<<64, 768, 0, stream>>>(xp, Whh32, hstate, pooled, out, s0, CH);
  }
  outproj<<<16, 128, 0, stream>>>(pooled, Wout, bout, flag, out);
}

// Round 8
// 1882.906 us; speedup vs baseline: 1.2846x; 1.2846x over previous
//
#include <hip/hip_runtime.h>

typedef unsigned short u16;
typedef unsigned int   u32;
typedef unsigned long long u64;
typedef short s16x8 __attribute__((ext_vector_type(8)));
typedef float f32x4 __attribute__((ext_vector_type(4)));
typedef u32   u32x2 __attribute__((ext_vector_type(2)));
typedef _Float16 f16x2 __attribute__((ext_vector_type(2)));

#define S_LEN 2048
#define BATCH 64
#define H_DIM 300
#define HP    304   // padded N (output) dim
#define KP    320   // padded K (contraction) dim

// ws layout (bytes)
#define OFF_WPAD 0u         // 304*320*2 = 194,560
#define OFF_BIAS 196608u    // 304*4
#define OFF_FLAG 198656u    // 4
#define OFF_H    200704u    // 64*160*4 = 40,960 (f16-pair packed h state)
#define OFF_POOL 278528u    // 2048*304*4 = 2,490,368
#define OFF_WHH  2768896u   // 320*160*4 = 204,800 (f16-pair packed W_hh)
#define OFF_XP   3158016u   // CH*64*304*4 (f32)

__device__ __forceinline__ float bf2f(u16 u){
  union { u32 i; float f; } v; v.i = ((u32)u) << 16; return v.f;
}
__device__ __forceinline__ u16 f2bf(float f){
  u32 i = __float_as_uint(f);
  u32 r = (i + 0x7fffu + ((i >> 16) & 1u)) >> 16;
  return (u16)r;
}
__device__ __forceinline__ f16x2 asH2(u32 u){
  union { u32 u; f16x2 h; } v; v.u = u; return v.h;
}
__device__ __forceinline__ u16 f2h(float f){
  union { _Float16 h; u16 u; } v; v.h = (_Float16)f; return v.u;
}

// v_dot2_f32_f16: c += a.x*b.x + a.y*b.y (f16 inputs, f32 accumulate)
#if __has_builtin(__builtin_amdgcn_fdot2)
#define FD(WU, HU, C) __builtin_amdgcn_fdot2(asH2(WU), asH2(HU), (C), false)
#else
__device__ __forceinline__ float fd_fb(u32 wu, u32 hu, float c){
  const f16x2 w = asH2(wu), h = asH2(hu);
  c = fmaf((float)w.x, (float)h.x, c);
  c = fmaf((float)w.y, (float)h.y, c);
  return c;
}
#define FD(WU, HU, C) fd_fb((WU), (HU), (C))
#endif

// ---------------------------------------------------------------------------
// detect: f32 vs bf16 input storage (bf16 emb exponents < 135 always).
// ---------------------------------------------------------------------------
__global__ __launch_bounds__(256) void detect(const u16* __restrict__ emb_raw,
                                              int* __restrict__ flag){
  __shared__ int big;
  if (threadIdx.x == 0) big = 0;
  __syncthreads();
  int loc = 0;
  for (int i = threadIdx.x; i < 1024; i += 256){
    const u32 e = ((u32)emb_raw[i] >> 7) & 0xFFu;
    if (e >= 135u) loc = 1;
  }
  if (loc) atomicOr(&big, 1);
  __syncthreads();
  if (threadIdx.x == 0) *flag = big;   // 1 = f32 inputs, 0 = bf16 inputs
}

// ---------------------------------------------------------------------------
// prep: zero pooled / packed hstate; padded bf16 W_ih [304][320]; fused fp32
// bias; f16-pair packed W_hh [320 rows][160 pairs] (zero padded).
// ---------------------------------------------------------------------------
__global__ __launch_bounds__(256) void prep(
    const void* __restrict__ Wih_raw, const void* __restrict__ Whh_raw,
    const void* __restrict__ bih_raw, const void* __restrict__ bhh_raw,
    const int* __restrict__ flag,
    u16* __restrict__ Wpad, u32* __restrict__ Whh16,
    float* __restrict__ biasp, float* __restrict__ pooled,
    u32* __restrict__ hstate)
{
  const bool isf32 = (*flag != 0);
  const int idx = blockIdx.x * 256 + threadIdx.x;
  if (idx < S_LEN * HP) pooled[idx] = 0.f;
  if (idx < BATCH * 160) hstate[idx] = 0u;
  if (idx < 320 * 160){
    const int r = idx / 160, j = idx % 160;
    const int k = 2 * j;
    float w0 = 0.f, w1 = 0.f;
    if (r < H_DIM){
      if (k < H_DIM)
        w0 = isf32 ? ((const float*)Whh_raw)[r * H_DIM + k]
                   : bf2f(((const u16*)Whh_raw)[r * H_DIM + k]);
      if (k + 1 < H_DIM)
        w1 = isf32 ? ((const float*)Whh_raw)[r * H_DIM + k + 1]
                   : bf2f(((const u16*)Whh_raw)[r * H_DIM + k + 1]);
    }
    Whh16[idx] = (u32)f2h(w0) | ((u32)f2h(w1) << 16);
  }
  if (idx < HP * KP){
    const int n = idx / KP, k = idx % KP;
    u16 v = 0;
    if (n < H_DIM && k < H_DIM){
      v = isf32 ? f2bf(((const float*)Wih_raw)[n * H_DIM + k])
                : ((const u16*)Wih_raw)[n * H_DIM + k];
    }
    Wpad[idx] = v;
  }
  if (idx < HP){
    float bv = 0.f;
    if (idx < H_DIM){
      bv = isf32 ? (((const float*)bih_raw)[idx] + ((const float*)bhh_raw)[idx])
                 : (bf2f(((const u16*)bih_raw)[idx]) + bf2f(((const u16*)bhh_raw)[idx]));
    }
    biasp[idx] = bv;
  }
}

// ---------------------------------------------------------------------------
// xp_gemm: xp[mrel][n] = emb[x[s0*64+mrel]] . W_ih[n,:] + b_ih[n] + b_hh[n]
// One block = 64 m-rows, 4 waves, MFMA 16x16x32 bf16. xp stored f32.
// ---------------------------------------------------------------------------
__global__ __launch_bounds__(256) void xp_gemm(
    const int* __restrict__ x, const void* __restrict__ emb_raw,
    const int* __restrict__ flag,
    const u16* __restrict__ Wpad, const float* __restrict__ biasp,
    float* __restrict__ xp, int s0)
{
  __shared__ u16 A[64 * KP];                 // 40 KB
  const bool isf32 = (*flag != 0);
  const int tid = threadIdx.x;
  const int m0g = s0 * BATCH + blockIdx.x * 64;   // global m of row 0
  const int m0r = blockIdx.x * 64;                // chunk-relative

  for (int t = tid; t < 640; t += 256){
    const int row = t / 10, wd = t % 10;
    *(u32*)&A[row * KP + H_DIM + wd * 2] = 0u;
  }
  for (int t = tid; t < 64 * 75; t += 256){
    const int row = t / 75, off = t % 75;
    const int tok = x[m0g + row];
    u64 pk;
    if (isf32){
      const float4 v = *(const float4*)((const float*)emb_raw + (size_t)tok * H_DIM + off * 4);
      pk = (u64)f2bf(v.x) | ((u64)f2bf(v.y) << 16)
         | ((u64)f2bf(v.z) << 32) | ((u64)f2bf(v.w) << 48);
    } else {
      pk = *(const u64*)((const u16*)emb_raw + (size_t)tok * H_DIM + off * 4);
    }
    *(u64*)&A[row * KP + off * 4] = pk;
  }
  __syncthreads();

  const int wave = tid >> 6, lane = tid & 63;
  const int lm = lane & 15, lq = lane >> 4;

  f32x4 acc[19];
#pragma unroll
  for (int nt = 0; nt < 19; ++nt) acc[nt] = (f32x4){0.f, 0.f, 0.f, 0.f};

#pragma unroll
  for (int ks = 0; ks < 10; ++ks){
    const int k = ks * 32 + lq * 8;
    const s16x8 af = *(const s16x8*)&A[(wave * 16 + lm) * KP + k];
#pragma unroll
    for (int nt = 0; nt < 19; ++nt){
      const s16x8 bf = *(const s16x8*)&Wpad[(nt * 16 + lm) * KP + k];
      acc[nt] = __builtin_amdgcn_mfma_f32_16x16x32_bf16(af, bf, acc[nt], 0, 0, 0);
    }
  }
#pragma unroll
  for (int nt = 0; nt < 19; ++nt){
    const int n = nt * 16 + lm;
    const float bv = biasp[n];
#pragma unroll
    for (int rr = 0; rr < 4; ++rr){
      const int m = m0r + wave * 16 + lq * 4 + rr;
      xp[(size_t)m * HP + n] = acc[nt][rr] + bv;
    }
  }
}

// ---------------------------------------------------------------------------
// recur: one block per batch b. 1024 threads = 16 waves. Wave c owns k-pair
// chunk [10c, 10c+10) (f16 pairs; 160 pairs = K padded 320). Lane l owns
// rows {4l..4l+3, 256+l}. Weights: 50 packed dwords/thread as 25 named
// u32x2 SSA values — small enough to fit UNDER the allocator's preferred
// 84-VGPR budget (R5-R7: 125-dword sets always got spilled/remat'd ->
// L2-BW bound). Dot via v_dot2_f32_f16 (2 MAC/lane/instr, f32 accum).
// h kept as f16 pairs in LDS; per-wave broadcast = 5 uniform ds_read_b64.
// ---------------------------------------------------------------------------
__global__ __launch_bounds__(1024) void recur(
    const float* __restrict__ xp, const u32* __restrict__ Whh16,
    u32* __restrict__ hstate, float* __restrict__ pooled,
    float* __restrict__ dout, int s0, int len)
{
  const int b   = blockIdx.x;
  const int tid = threadIdx.x;
  const int c   = tid >> 6;        // k-pair chunk 0..15
  const int l   = tid & 63;
  const int j0  = c * 10;          // first pair index
  const int r0  = l * 4;           // rows r0..r0+3
  const int r4  = 256 + l;         // 5th row (rows 300..319 zero pad)

  __shared__ float part[16 * 320]; // 20.5 KB
  __shared__ u32 hp[160];          // h as f16 pairs (entries 150..159 pad=0)

  u32x2 qa0,qb0,qc0,qd0,qe0;
  u32x2 qa1,qb1,qc1,qd1,qe1;
  u32x2 qa2,qb2,qc2,qd2,qe2;
  u32x2 qa3,qb3,qc3,qd3,qe3;
  u32x2 qa4,qb4,qc4,qd4,qe4;

#define LOADW(R, ROW) { const u32* wp = Whh16 + (size_t)(ROW) * 160 + j0; \
  qa##R = *(const u32x2*)(wp + 0); qb##R = *(const u32x2*)(wp + 2);       \
  qc##R = *(const u32x2*)(wp + 4); qd##R = *(const u32x2*)(wp + 6);       \
  qe##R = *(const u32x2*)(wp + 8); }
  LOADW(0, r0)
  LOADW(1, r0 + 1)
  LOADW(2, r0 + 2)
  LOADW(3, r0 + 3)
  LOADW(4, r4)
#undef LOADW

  if (tid < 160) hp[tid] = hstate[b * 160 + tid];

  const float* xpb = xp + (size_t)b * HP;        // chunk row t -> t*64+b
  float xv = 0.f;
  if (tid < 304) xv = xpb[tid];
  __syncthreads();

  for (int t = 0; t < len; ++t){
    float xnext = 0.f;
    if (tid < 304){
      const int tn = (t + 1 < len) ? (t + 1) : t;
      xnext = xpb[(size_t)tn * (BATCH * HP) + tid];
    }
    // wave-uniform h broadcast: 5 x ds_read_b64 (8B-aligned, conflict-free)
    const u32x2 h0 = *(const u32x2*)&hp[j0 + 0];
    const u32x2 h1 = *(const u32x2*)&hp[j0 + 2];
    const u32x2 h2 = *(const u32x2*)&hp[j0 + 4];
    const u32x2 h3 = *(const u32x2*)&hp[j0 + 6];
    const u32x2 h4 = *(const u32x2*)&hp[j0 + 8];

    float s0v, s1v, s2v, s3v, s4v;
#define DOTROW(R, DST) { float s = 0.f;                              \
    s = FD(qa##R.x, h0.x, s); s = FD(qa##R.y, h0.y, s);              \
    s = FD(qb##R.x, h1.x, s); s = FD(qb##R.y, h1.y, s);              \
    s = FD(qc##R.x, h2.x, s); s = FD(qc##R.y, h2.y, s);              \
    s = FD(qd##R.x, h3.x, s); s = FD(qd##R.y, h3.y, s);              \
    s = FD(qe##R.x, h4.x, s); s = FD(qe##R.y, h4.y, s); DST = s; }
    DOTROW(0, s0v)
    DOTROW(1, s1v)
    DOTROW(2, s2v)
    DOTROW(3, s3v)
    DOTROW(4, s4v)
#undef DOTROW

    *(f32x4*)&part[c * 320 + r0] = (f32x4){s0v, s1v, s2v, s3v};
    part[c * 320 + r4] = s4v;
    __syncthreads();

    if (tid < 304){
      float sum = xv;
#pragma unroll
      for (int cc = 0; cc < 16; ++cc) sum += part[cc * 320 + tid];
      const float h = fmaxf(sum, 0.f);
      const int s = s0 + t;
      if (tid < H_DIM){
        atomicMax((u32*)(pooled + (size_t)s * HP + tid), __float_as_uint(h));
        if (s == S_LEN - 1) dout[S_LEN * 2 + b * H_DIM + tid] = h;
      }
      ((u16*)hp)[tid] = f2h(h);
      xv = xnext;
    }
    __syncthreads();
  }
  if (tid < 160) hstate[b * 160 + tid] = hp[tid];
}

// ---------------------------------------------------------------------------
// outproj: out[s][c] = sum_i pooled[s][i] * W_out[c][i] + b_out[c]  (f32 out)
// ---------------------------------------------------------------------------
__global__ __launch_bounds__(128) void outproj(
    const float* __restrict__ pooled, const void* __restrict__ Wout_raw,
    const void* __restrict__ bout_raw, const int* __restrict__ flag,
    float* __restrict__ dout)
{
  const bool isf32 = (*flag != 0);
  const int s = blockIdx.x * 128 + threadIdx.x;   // 0..2047
  float a0, a1;
  if (isf32){ a0 = ((const float*)bout_raw)[0]; a1 = ((const float*)bout_raw)[1]; }
  else      { a0 = bf2f(((const u16*)bout_raw)[0]); a1 = bf2f(((const u16*)bout_raw)[1]); }
  for (int i = 0; i < H_DIM; ++i){
    const float p = pooled[(size_t)s * HP + i];
    float w0, w1;
    if (isf32){ w0 = ((const float*)Wout_raw)[i]; w1 = ((const float*)Wout_raw)[H_DIM + i]; }
    else      { w0 = bf2f(((const u16*)Wout_raw)[i]); w1 = bf2f(((const u16*)Wout_raw)[H_DIM + i]); }
    a0 = fmaf(p, w0, a0);
    a1 = fmaf(p, w1, a1);
  }
  dout[s * 2 + 0] = a0;
  dout[s * 2 + 1] = a1;
}

// ---------------------------------------------------------------------------
extern "C" void kernel_launch(void* const* d_in, const int* in_sizes, int n_in,
                              void* d_out, int out_size, void* d_ws, size_t ws_size,
                              hipStream_t stream)
{
  const int* x  = (const int*)d_in[0];
  const void* emb  = d_in[1];
  const void* Wih  = d_in[2];
  const void* Whh  = d_in[3];
  const void* bih  = d_in[4];
  const void* bhh  = d_in[5];
  const void* Wout = d_in[6];
  const void* bout = d_in[7];
  float* out = (float*)d_out;

  char* ws = (char*)d_ws;
  u16*   Wpad   = (u16*)(ws + OFF_WPAD);
  float* biasp  = (float*)(ws + OFF_BIAS);
  int*   flag   = (int*)(ws + OFF_FLAG);
  u32*   hstate = (u32*)(ws + OFF_H);
  float* pooled = (float*)(ws + OFF_POOL);
  u32*   Whh16  = (u32*)(ws + OFF_WHH);
  float* xp     = (float*)(ws + OFF_XP);

  // choose chunk size (steps) so OFF_XP + CH*64*304*4 fits in ws_size
  const size_t per_step = (size_t)BATCH * HP * 4;   // 77,824 B
  int CH = 16;
  const int cands[8] = {2048, 1024, 512, 256, 128, 64, 32, 16};
  for (int i = 0; i < 8; ++i){
    if ((size_t)OFF_XP + (size_t)cands[i] * per_step <= ws_size){ CH = cands[i]; break; }
  }
  const int nchunks = S_LEN / CH;

  detect<<<1, 256, 0, stream>>>((const u16*)emb, flag);
  prep<<<2432, 256, 0, stream>>>(Wih, Whh, bih, bhh, flag, Wpad, Whh16,
                                 biasp, pooled, hstate);
  for (int k = 0; k < nchunks; ++k){
    const int s0 = k * CH;
    xp_gemm<<<CH, 256, 0, stream>>>(x, emb, flag, Wpad, biasp, xp, s0);
    recur<<<64, 1024, 0, stream>>>(xp, Whh16, hstate, pooled, out, s0, CH);
  }
  outproj<<<16, 128, 0, stream>>>(pooled, Wout, bout, flag, out);
}